// Round 1
// 170.220 us; speedup vs baseline: 1.0304x; 1.0304x over previous
//
#include <hip/hip_runtime.h>
#include <stdint.h>

#define B_ 2
#define T_ 2048
#define C_ 1024
#define H_ 16
#define DH_ 64
#define M_ (B_*T_)   // 4096

typedef short bhalf8 __attribute__((ext_vector_type(8)));
typedef float floatx4 __attribute__((ext_vector_type(4)));

__device__ __forceinline__ short f2bf(float f) {
  unsigned u = __float_as_uint(f);
  u += 0x7fffu + ((u >> 16) & 1u);   // round-to-nearest-even
  return (short)(u >> 16);
}
__device__ __forceinline__ float bf2f(short s) {
  return __uint_as_float(((unsigned)(unsigned short)s) << 16);
}

// async global->LDS, 16B per lane; lds_dst wave-uniform (lane -> +lane*16)
__device__ __forceinline__ void gll16(void* lds_dst, const void* g_src) {
  __builtin_amdgcn_global_load_lds(
      reinterpret_cast<const uint32_t __attribute__((address_space(1)))*>(
          reinterpret_cast<uintptr_t>(g_src)),
      reinterpret_cast<uint32_t __attribute__((address_space(3)))*>(
          reinterpret_cast<uintptr_t>(lds_dst)),
      16, 0, 0);
}

__global__ void cvt_all(
    const float* __restrict__ x,  const float* __restrict__ wq,
    const float* __restrict__ wk, const float* __restrict__ wv,
    const float* __restrict__ wo,
    short* __restrict__ xb, short* __restrict__ wqb, short* __restrict__ wkb,
    short* __restrict__ wvb, short* __restrict__ wob)
{
  int i = blockIdx.x * blockDim.x + threadIdx.x;
  const float* s; short* d; int off;
  if (i < (M_*C_/4)) { s = x; d = xb; off = i; }
  else {
    int j = i - M_*C_/4;
    int w = j >> 18;                     // C_*C_/4 == 1<<18
    off = j & ((1<<18) - 1);
    s = (w==0) ? wq : (w==1) ? wk : (w==2) ? wv : wo;
    d = (w==0) ? wqb : (w==1) ? wkb : (w==2) ? wvb : wob;
  }
  float4 v = ((const float4*)s)[off];
  short4 o;
  o.x = f2bf(v.x); o.y = f2bf(v.y); o.z = f2bf(v.z); o.w = f2bf(v.w);
  ((short4*)d)[off] = o;
}

// R10: fused Q/K/V projection, 256x256 tile, BK=64, 8 waves (2Mx4N),
// 128 KiB LDS, deep pipeline with counted vmcnt (no vmcnt(0) in main loop).
// Grid 192 = 12 N-tiles (x<4 Q, x<8 K, x>=8 V; V swaps operands so C/D
// layout gives coalesced V^T store) x 16 M-tiles, XCD-swizzled.
//
// Per K-tile t (buf = t&1): 4 phases, phase = (ks, mh):
//   p1: ds_read A[0..3]@ks0 + B[0..3]@ks0 ; stage(t+1) B q0,q1
//   p2: ds_read A[4..7]@ks0               ; stage(t+1) B q2,q3
//   p3: ds_read A[0..3]@ks1 + B[0..3]@ks1 ; stage(t+1) A q0,q2
//   p4: ds_read A[4..7]@ks1               ; stage(t+1) A q1,q3
// Each phase: reads+stage -> s_barrier -> lgkmcnt(0) -> setprio(1) ->
// 16 MFMA -> setprio(0) -> vmcnt gate -> s_barrier.
// Staging for t+1 targets buf[t^1] which holds tile t-1, fully retired at
// t-1.p4's trailing barrier, so no read/write aliasing. Read-side gates:
//   end-p1 vmcnt(2): waits prev-p4-staged A q1,q3 (read in p2)
//   end-p2 vmcnt(4), end-p3 vmcnt(6): slack only
//   end-p4 vmcnt(2): waits B q* (p1,p2) + A q0,q2 (p3) for next tile's p1
// LDS granule swizzle: slot (row, g) holds global granule g^(row&7);
// reads use granule ((ks*4+quad)^(row&7)) -> conflict-free b128.
__global__ __launch_bounds__(512, 2) void gemm_qkv(
    const short* __restrict__ X,
    const short* __restrict__ Wq, const short* __restrict__ Wk, const short* __restrict__ Wv,
    short* __restrict__ Qb, short* __restrict__ Kb, short* __restrict__ Vt)
{
  __shared__ __align__(16) short As[2][256*64];   // 32 KB per buf
  __shared__ __align__(16) short Bs[2][256*64];   // 32 KB per buf
  const int tid  = threadIdx.x;
  const int lane = tid & 63;
  const int wid  = tid >> 6;
  const int l15  = lane & 15;
  const int quad = lane >> 4;
  const int wr   = wid >> 2;          // 0..1  (M half)
  const int wc   = wid & 3;           // 0..3  (N quarter)
  const int K    = C_;

  // XCD-aware swizzle: 192 % 8 == 0, consecutive wg share m-tile in runs of 12
  const int bid = blockIdx.x;
  const int wg  = (bid & 7) * 24 + (bid >> 3);
  const int nx  = wg % 12;
  const int m0  = (wg / 12) << 8;

  int kind, nloc;                    // 0=Q 1=K 2=V
  const short *Ab, *Bb;
  if (nx < 4)      { kind = 0; nloc = nx << 8;       Ab = X  + (size_t)m0*K;   Bb = Wq + (size_t)nloc*K; }
  else if (nx < 8) { kind = 1; nloc = (nx - 4) << 8; Ab = X  + (size_t)m0*K;   Bb = Wk + (size_t)nloc*K; }
  else             { kind = 2; nloc = (nx - 8) << 8; Ab = Wv + (size_t)nloc*K; Bb = X  + (size_t)m0*K;   }

  const int r_loc = tid >> 3;        // 0..63: row within a 64-row quarter
  const int g_lin = tid & 7;         // linear granule (16B) within row

  // stage one 8 KB quarter-unit (64 rows x 64 shorts): 1 gll16/thread
  auto stageU = [&](short* lds, const short* g, int q, int k0) {
    int row = (q << 6) + r_loc;
    int gs  = g_lin ^ (row & 7);     // pre-swizzled global source (m173)
    gll16(lds + (q << 12) + (wid << 9), g + (size_t)row * K + k0 + (gs << 3));
  };

  floatx4 acc[8][4] = {};

  // ---- prologue: stage tile 0; order = read priority of tile0.p1/p2 ----
  stageU(&Bs[0][0], Bb, 0, 0); stageU(&Bs[0][0], Bb, 1, 0);
  stageU(&Bs[0][0], Bb, 2, 0); stageU(&Bs[0][0], Bb, 3, 0);
  stageU(&As[0][0], Ab, 0, 0); stageU(&As[0][0], Ab, 2, 0);
  stageU(&As[0][0], Ab, 1, 0); stageU(&As[0][0], Ab, 3, 0);
  asm volatile("s_waitcnt vmcnt(2)" ::: "memory");   // allow A q1,q3 in flight
  __builtin_amdgcn_s_barrier();
  __builtin_amdgcn_sched_barrier(0);

  for (int t = 0; t < 16; ++t) {
    const int buf = t & 1, nbuf = buf ^ 1;
    const int kn = (t + 1) << 6;
    const bool pf = (t < 15);
    bhalf8 aF[4], bF[4];

    // -------- phase 1: ks=0, m-frags 0..3 (+ B ks=0) --------
#pragma unroll
    for (int i = 0; i < 4; ++i) {
      int row = (wr << 7) + (i << 4) + l15;
      aF[i] = *(const bhalf8*)&As[buf][(row << 6) + ((quad ^ (row & 7)) << 3)];
    }
#pragma unroll
    for (int n = 0; n < 4; ++n) {
      int row = (wc << 6) + (n << 4) + l15;
      bF[n] = *(const bhalf8*)&Bs[buf][(row << 6) + ((quad ^ (row & 7)) << 3)];
    }
    if (pf) { stageU(&Bs[nbuf][0], Bb, 0, kn); stageU(&Bs[nbuf][0], Bb, 1, kn); }
    __builtin_amdgcn_s_barrier();
    asm volatile("s_waitcnt lgkmcnt(0)" ::: "memory");
    __builtin_amdgcn_sched_barrier(0);
    __builtin_amdgcn_s_setprio(1);
#pragma unroll
    for (int i = 0; i < 4; ++i)
#pragma unroll
      for (int n = 0; n < 4; ++n)
        acc[i][n] = __builtin_amdgcn_mfma_f32_16x16x32_bf16(aF[i], bF[n], acc[i][n], 0, 0, 0);
    __builtin_amdgcn_s_setprio(0);
    asm volatile("s_waitcnt vmcnt(2)" ::: "memory");
    __builtin_amdgcn_s_barrier();
    __builtin_amdgcn_sched_barrier(0);

    // -------- phase 2: ks=0, m-frags 4..7 (reuse bF) --------
#pragma unroll
    for (int i = 0; i < 4; ++i) {
      int row = (wr << 7) + ((4 + i) << 4) + l15;
      aF[i] = *(const bhalf8*)&As[buf][(row << 6) + ((quad ^ (row & 7)) << 3)];
    }
    if (pf) { stageU(&Bs[nbuf][0], Bb, 2, kn); stageU(&Bs[nbuf][0], Bb, 3, kn); }
    __builtin_amdgcn_s_barrier();
    asm volatile("s_waitcnt lgkmcnt(0)" ::: "memory");
    __builtin_amdgcn_sched_barrier(0);
    __builtin_amdgcn_s_setprio(1);
#pragma unroll
    for (int i = 0; i < 4; ++i)
#pragma unroll
      for (int n = 0; n < 4; ++n)
        acc[4 + i][n] = __builtin_amdgcn_mfma_f32_16x16x32_bf16(aF[i], bF[n], acc[4 + i][n], 0, 0, 0);
    __builtin_amdgcn_s_setprio(0);
    asm volatile("s_waitcnt vmcnt(4)" ::: "memory");
    __builtin_amdgcn_s_barrier();
    __builtin_amdgcn_sched_barrier(0);

    // -------- phase 3: ks=1, m-frags 0..3 (+ B ks=1) --------
#pragma unroll
    for (int i = 0; i < 4; ++i) {
      int row = (wr << 7) + (i << 4) + l15;
      aF[i] = *(const bhalf8*)&As[buf][(row << 6) + (((4 + quad) ^ (row & 7)) << 3)];
    }
#pragma unroll
    for (int n = 0; n < 4; ++n) {
      int row = (wc << 6) + (n << 4) + l15;
      bF[n] = *(const bhalf8*)&Bs[buf][(row << 6) + (((4 + quad) ^ (row & 7)) << 3)];
    }
    if (pf) { stageU(&As[nbuf][0], Ab, 0, kn); stageU(&As[nbuf][0], Ab, 2, kn); }
    __builtin_amdgcn_s_barrier();
    asm volatile("s_waitcnt lgkmcnt(0)" ::: "memory");
    __builtin_amdgcn_sched_barrier(0);
    __builtin_amdgcn_s_setprio(1);
#pragma unroll
    for (int i = 0; i < 4; ++i)
#pragma unroll
      for (int n = 0; n < 4; ++n)
        acc[i][n] = __builtin_amdgcn_mfma_f32_16x16x32_bf16(aF[i], bF[n], acc[i][n], 0, 0, 0);
    __builtin_amdgcn_s_setprio(0);
    asm volatile("s_waitcnt vmcnt(6)" ::: "memory");
    __builtin_amdgcn_s_barrier();
    __builtin_amdgcn_sched_barrier(0);

    // -------- phase 4: ks=1, m-frags 4..7 (reuse bF) --------
#pragma unroll
    for (int i = 0; i < 4; ++i) {
      int row = (wr << 7) + ((4 + i) << 4) + l15;
      aF[i] = *(const bhalf8*)&As[buf][(row << 6) + (((4 + quad) ^ (row & 7)) << 3)];
    }
    if (pf) { stageU(&As[nbuf][0], Ab, 1, kn); stageU(&As[nbuf][0], Ab, 3, kn); }
    __builtin_amdgcn_s_barrier();
    asm volatile("s_waitcnt lgkmcnt(0)" ::: "memory");
    __builtin_amdgcn_sched_barrier(0);
    __builtin_amdgcn_s_setprio(1);
#pragma unroll
    for (int i = 0; i < 4; ++i)
#pragma unroll
      for (int n = 0; n < 4; ++n)
        acc[4 + i][n] = __builtin_amdgcn_mfma_f32_16x16x32_bf16(aF[i], bF[n], acc[4 + i][n], 0, 0, 0);
    __builtin_amdgcn_s_setprio(0);
    asm volatile("s_waitcnt vmcnt(2)" ::: "memory");
    __builtin_amdgcn_s_barrier();
    __builtin_amdgcn_sched_barrier(0);
  }

  if (kind < 2) {                        // Q or K: RoPE epilogue -> (B,H,T,DH)
    short* Cb = kind ? Kb : Qb;
    const int hh = (nloc + (wc << 6)) >> 6;     // wave's 64-col chunk = 1 head
    const float frq0 = exp2f((float)l15        * (-0.4152410118609203f));
    const float frq1 = exp2f((float)(l15 + 16) * (-0.4152410118609203f));
#pragma unroll
    for (int m = 0; m < 8; ++m)
#pragma unroll
      for (int r = 0; r < 4; ++r) {
        int n  = m0 + (wr << 7) + (m << 4) + (quad << 2) + r;
        int bb = n >> 11, tt = n & (T_ - 1);
        size_t base = ((size_t)(bb * H_ + hh) * T_ + tt) * DH_;
        float tf = (float)tt;
        {
          float ang = tf * frq0;
          float sn = __sinf(ang), cs = __cosf(ang);
          float xlo = acc[m][0][r], xhi = acc[m][2][r];
          Cb[base + l15]      = f2bf(xlo * cs - xhi * sn);
          Cb[base + l15 + 32] = f2bf(xhi * cs + xlo * sn);
        }
        {
          float ang = tf * frq1;
          float sn = __sinf(ang), cs = __cosf(ang);
          float xlo = acc[m][1][r], xhi = acc[m][3][r];
          Cb[base + l15 + 16] = f2bf(xlo * cs - xhi * sn);
          Cb[base + l15 + 48] = f2bf(xhi * cs + xlo * sn);
        }
      }
  } else {                               // V: rows=channels, cols=tokens -> V^T
#pragma unroll
    for (int m = 0; m < 8; ++m)
#pragma unroll
      for (int r = 0; r < 4; ++r) {
        int o = nloc + (wr << 7) + (m << 4) + (quad << 2) + r;
#pragma unroll
        for (int n = 0; n < 4; ++n) {
          int tk = m0 + (wc << 6) + (n << 4) + l15;
          int bb = tk >> 11, tt = tk & (T_ - 1);
          Vt[(size_t)bb * (C_ * T_) + (size_t)o * T_ + tt] = f2bf(acc[m][n][r]);
        }
      }
  }
}

// Final projection, single-barrier dbuf structure. LDS 24 KB.
__global__ __launch_bounds__(256) void gemm_out(
    const short* __restrict__ A, const short* __restrict__ Bm, float* __restrict__ Cf)
{
  __shared__ __align__(16) short As[2][128*32];   // 8 KB per buf
  __shared__ __align__(16) short Bs[2][64*32];    // 4 KB per buf
  const int tid = threadIdx.x, lane = tid & 63, wv = tid >> 6;
  const int l15 = lane & 15, quad = lane >> 4;
  const int n0 = blockIdx.x << 6;
  const int m0 = blockIdx.y << 7;

  const short* Ab = A  + (size_t)m0 * C_;
  const short* Bb = Bm + (size_t)n0 * C_;

  auto stage = [&](int buf, int k0) {
#pragma unroll
    for (int i = 0; i < 2; ++i) {
      int p = (i<<8) + tid, r = p >> 2, go = (p & 3) ^ ((r >> 1) & 3);
      gll16(&As[buf][((i<<8) + (wv<<6))*8], Ab + (size_t)r*C_ + k0 + (go<<3));
    }
    {
      int p = tid, r = p >> 2, go = (p & 3) ^ ((r >> 1) & 3);
      gll16(&Bs[buf][(wv<<6)*8], Bb + (size_t)r*C_ + k0 + (go<<3));
    }
  };

  floatx4 acc[2][4] = {};
  stage(0, 0);
  int cur = 0;
  for (int it = 0; it < 32; ++it) {
    __syncthreads();
    if (it < 31) stage(cur ^ 1, (it + 1) << 5);
    bhalf8 af[2], bfr[4];
#pragma unroll
    for (int rt = 0; rt < 2; ++rt) {
      int row = (wv<<5) + rt*16 + l15;
      af[rt] = *(const bhalf8*)&As[cur][(row<<5) + ((quad ^ ((row>>1)&3))<<3)];
    }
#pragma unroll
    for (int ct = 0; ct < 4; ++ct) {
      int row = ct*16 + l15;
      bfr[ct] = *(const bhalf8*)&Bs[cur][(row<<5) + ((quad ^ ((row>>1)&3))<<3)];
    }
#pragma unroll
    for (int rt = 0; rt < 2; ++rt)
#pragma unroll
      for (int ct = 0; ct < 4; ++ct)
        acc[rt][ct] = __builtin_amdgcn_mfma_f32_16x16x32_bf16(af[rt], bfr[ct], acc[rt][ct], 0, 0, 0);
    cur ^= 1;
  }

#pragma unroll
  for (int rt = 0; rt < 2; ++rt)
#pragma unroll
    for (int r = 0; r < 4; ++r) {
      int n = m0 + (wv<<5) + rt*16 + quad*4 + r;
#pragma unroll
      for (int ct = 0; ct < 4; ++ct)
        Cf[(size_t)n * C_ + n0 + ct*16 + l15] = acc[rt][ct][r];
    }
}

// K (B,H,T,DH) -> Kt (B,H,DH,T). Grid 1024 = bh*32 + token-chunk.
__global__ __launch_bounds__(256) void transpose_k(
    const short* __restrict__ Kb, short* __restrict__ Kt)
{
  __shared__ short tile[64*66];
  const int idx = blockIdx.x, bh = idx >> 5, tc = idx & 31;
  const int t0 = tc << 6;
  const short* src = Kb + ((size_t)bh*T_ + t0) * DH_;
  int row = threadIdx.x >> 2, c0 = (threadIdx.x & 3) << 4;
  *(int4*)&tile[row*66 + c0]     = *(const int4*)&src[row*64 + c0];
  *(int4*)&tile[row*66 + c0 + 8] = *(const int4*)&src[row*64 + c0 + 8];
  __syncthreads();
  short* dst = Kt + (size_t)bh*DH_*T_;
  int d = threadIdx.x >> 2, k0 = (threadIdx.x & 3) << 4;
  short tmp[16];
#pragma unroll
  for (int i = 0; i < 16; ++i) tmp[i] = tile[(k0 + i)*66 + d];
  *(int4*)&dst[(size_t)d*T_ + t0 + k0]     = *(const int4*)&tmp[0];
  *(int4*)&dst[(size_t)d*T_ + t0 + k0 + 8] = *(const int4*)&tmp[8];
}

// Per-segment state summaries. 256 blocks = bh*8 + p, single-barrier dbuf.
__global__ __launch_bounds__(256) void seg_state(
    const short* __restrict__ Kt, const short* __restrict__ Vt,
    short* __restrict__ Pseg)
{
  __shared__ __align__(16) short Ks[2][64*64];   // K^T [d][tok], swizzled
  __shared__ __align__(16) short Vs[2][64*64];   // V^T [e][tok], swizzled
  const int tid = threadIdx.x, lane = tid & 63, wv = tid >> 6;
  const int l15 = lane & 15, quad = lane >> 4;
  const int wrow = wv << 4;
  const int bh = blockIdx.x >> 3, p = blockIdx.x & 7;
  const int h = bh & 15;
  const float log2g = log2f(1.f - exp2f(-5.f - (float)h));
  const float g64 = exp2f(log2g * 64.f);

  float wgt[16];
#pragma unroll
  for (int ks = 0; ks < 2; ++ks)
#pragma unroll
    for (int i = 0; i < 8; ++i)
      wgt[ks*8 + i] = exp2f(log2g * (float)(64 - (ks*32 + (quad<<3) + i)));

  const short* Ktg = Kt + (size_t)bh*DH_*T_;
  const short* Vtg = Vt + (size_t)bh*DH_*T_;

  auto stage = [&](int buf, int jc) {
    const int m0 = ((p<<2) + jc) << 6;
#pragma unroll
    for (int i = 0; i < 2; ++i) {
      int slot = (i<<8) + tid;
      int r = slot >> 3, g = (slot & 7) ^ (r & 7);
      gll16(&Ks[buf][((i<<8) + (wv<<6))*8], Ktg + (size_t)r*T_ + m0 + (g<<3));
      gll16(&Vs[buf][((i<<8) + (wv<<6))*8], Vtg + (size_t)r*T_ + m0 + (g<<3));
    }
  };

  floatx4 acc[4] = {};
  stage(0, 0);
  int cur = 0;
  for (int j = 0; j < 4; ++j) {
    __syncthreads();
    if (j < 3) stage(cur ^ 1, j + 1);
#pragma unroll
    for (int ct = 0; ct < 4; ++ct)
#pragma unroll
      for (int r = 0; r < 4; ++r) acc[ct][r] *= g64;
#pragma unroll
    for (int ks = 0; ks < 2; ++ks) {
      int row = wrow + l15;
      bhalf8 va = *(const bhalf8*)&Vs[cur][(row<<6) + ((((ks<<2)+quad) ^ (row&7))<<3)];
      bhalf8 aw;
#pragma unroll
      for (int i = 0; i < 8; ++i) aw[i] = f2bf(bf2f(va[i]) * wgt[ks*8 + i]);
      bhalf8 bk[4];
#pragma unroll
      for (int ct = 0; ct < 4; ++ct) {
        int kr = ct*16 + l15;
        bk[ct] = *(const bhalf8*)&Ks[cur][(kr<<6) + ((((ks<<2)+quad) ^ (kr&7))<<3)];
      }
#pragma unroll
      for (int ct = 0; ct < 4; ++ct)
        acc[ct] = __builtin_amdgcn_mfma_f32_16x16x32_bf16(aw, bk[ct], acc[ct], 0, 0, 0);
    }
    cur ^= 1;
  }
  size_t base = (size_t)(bh*8 + p) * 2 * 4096;
#pragma unroll
  for (int ct = 0; ct < 4; ++ct)
#pragma unroll
    for (int r = 0; r < 4; ++r) {
      int e = wrow + (quad<<2) + r, d = ct*16 + l15;
      float x = acc[ct][r];
      short hi = f2bf(x);
      short lo = f2bf(x - bf2f(hi));
      Pseg[base + e*64 + d]        = hi;
      Pseg[base + 4096 + e*64 + d] = lo;
    }
}

// Chunked retention: grid 1024 uniform blocks = (bh, chunk).
__global__ __launch_bounds__(256) void retention_chunk(
    const short* __restrict__ Qb, const short* __restrict__ Kb,
    const short* __restrict__ Kt, const short* __restrict__ Vt,
    const short* __restrict__ Pseg,
    const float* __restrict__ gnw, const float* __restrict__ gnb,
    short* __restrict__ Xn)
{
  __shared__ __align__(16) short Vs[64*64];    // V^T [e][tok] (scan, then own)
  __shared__ __align__(16) short Kts[64*64];   // K^T [d][tok] (scan)
  __shared__ __align__(16) short KSs[64*64];   // K [tok][d], reused as Ss
  __shared__ __align__(16) short Sh[64*64];    // state hi [e][d]
  __shared__ __align__(16) short Sl[64*64];    // state lo [e][d]

  const int tid = threadIdx.x, lane = tid & 63, wv = tid >> 6;
  const int l15 = lane & 15, quad = lane >> 4;
  const int wrow = wv << 4;

  const int idx = blockIdx.x;
  const int bh = idx & 31;
  const int cc = idx >> 5;
  const int c  = ((cc & 7) << 2) | (cc >> 3);
  const int p = c >> 2, j = c & 3;
  const int b = bh >> 4, h = bh & 15;
  const int n0 = c << 6;

  const float log2g = log2f(1.f - exp2f(-5.f - (float)h));
  const float g64 = exp2f(log2g * 64.f);

  const short* Qg  = Qb + ((size_t)bh*T_ + n0 + wrow) * DH_;
  const short* Kg  = Kb + (size_t)bh*T_*DH_;
  const short* Ktg = Kt + (size_t)bh*DH_*T_;
  const short* Vtg = Vt + (size_t)bh*DH_*T_;

  bhalf8 aq[2];
#pragma unroll
  for (int ks = 0; ks < 2; ++ks)
    aq[ks] = *(const bhalf8*)(Qg + (size_t)l15*DH_ + ks*32 + quad*8);

  float rowf[4], colf0[4];
#pragma unroll
  for (int r = 0; r < 4; ++r)
    rowf[r] = exp2f(log2g * (float)(wrow + (quad<<2) + r)) * 0.125f;
#pragma unroll
  for (int ct = 0; ct < 4; ++ct)
    colf0[ct] = exp2f(-log2g * (float)(ct*16 + l15));

  const bool has_state = (c > 0);

  // ---- state scan over own-segment chunks 0..j-1 ----
  floatx4 st[4] = {};
  if (j > 0) {
    float wgt[16];
#pragma unroll
    for (int ks = 0; ks < 2; ++ks)
#pragma unroll
      for (int i = 0; i < 8; ++i)
        wgt[ks*8 + i] = exp2f(log2g * (float)(64 - (ks*32 + (quad<<3) + i)));
    for (int jp = 0; jp < j; ++jp) {
      if (log2g * (float)((j - 1 - jp) << 6) < -34.f) continue; // fully decayed
      const int m0 = ((p<<2) + jp) << 6;
      __syncthreads();
#pragma unroll
      for (int i = 0; i < 2; ++i) {
        int slot = (i<<8) + tid;
        int r = slot >> 3, g = (slot & 7) ^ (r & 7);
        gll16(&Kts[((i<<8) + (wv<<6))*8], Ktg + (size_t)r*T_ + m0 + (g<<3));
        gll16(&Vs[((i<<8) + (wv<<6))*8],  Vtg + (size_t)r*T_ + m0 + (g<<3));
      }
      __syncthreads();
#pragma unroll
      for (int ct = 0; ct < 4; ++ct)
#pragma unroll
        for (int r = 0; r < 4; ++r) st[ct][r] *= g64;
#pragma unroll
      for (int ks = 0; ks < 2; ++ks) {
        int row = wrow + l15;
        bhalf8 va = *(const bhalf8*)&Vs[(row<<6) + ((((ks<<2)+quad) ^ (row&7))<<3)];
        bhalf8 aw;
#pragma unroll
        for (int i = 0; i < 8; ++i) aw[i] = f2bf(bf2f(va[i]) * wgt[ks*8 + i]);
        bhalf8 bk[4];
#pragma unroll
        for (int ct = 0; ct < 4; ++ct) {
          int kr = ct*16 + l15;
          bk[ct] = *(const bhalf8*)&Kts[(kr<<6) + ((((ks<<2)+quad) ^ (kr&7))<<3)];
        }
#pragma unroll
        for (int ct = 0; ct < 4; ++ct)
          st[ct] = __builtin_amdgcn_mfma_f32_16x16x32_bf16(aw, bk[ct], st[ct], 0, 0, 0);
      }
    }
  }
  // ---- add weighted previous-segment summaries (256-token segments) ----
  for (int pp = 0; pp < p; ++pp) {
    float wexp = log2g * (float)(n0 - ((pp + 1) << 8));
    if (wexp < -34.f) continue;
    float w = exp2f(wexp);
    const short* Pg = Pseg + (size_t)(bh*8 + pp) * 2 * 4096;
#pragma unroll
    for (int ct = 0; ct < 4; ++ct)
#pragma unroll
      for (int r = 0; r < 4; ++r) {
        int e = wrow + (quad<<2) + r, d = ct*16 + l15;
        st[ct][r] += w * (bf2f(Pg[e*64 + d]) + bf2f(Pg[4096 + e*64 + d]));
      }
  }
  // ---- split state to bf16 hi/lo in LDS ----
  if (has_state) {
#pragma unroll
    for (int ct = 0; ct < 4; ++ct)
#pragma unroll
      for (int r = 0; r < 4; ++r) {
        int e = wrow + (quad<<2) + r, d = ct*16 + l15;
        float x = st[ct][r];
        short hi = f2bf(x);
        short lo = f2bf(x - bf2f(hi));
        int addr = (e<<6) + ((((d>>3) ^ (e&7))<<3)) + (d&7);
        Sh[addr] = hi; Sl[addr] = lo;
      }
  }

  // ---- stage own chunk: K token-major + V^T ----
  __syncthreads();                     // covers Sh/Sl writes + frees Vs/Kts
#pragma unroll
  for (int i = 0; i < 2; ++i) {
    int slot = (i<<8) + tid;
    int r = slot >> 3, g = (slot & 7) ^ (r & 7);
    gll16(&KSs[((i<<8) + (wv<<6))*8], Kg  + (size_t)(n0 + r)*DH_ + (g<<3));
    gll16(&Vs[((i<<8) + (wv<<6))*8],  Vtg + (size_t)r*T_ + n0 + (g<<3));
  }
  __syncthreads();

  // ---- intra: QK^T on diagonal chunk ----
  floatx4 sacc[4] = {};
#pragma unroll
  for (int ks = 0; ks < 2; ++ks) {
    bhalf8 bk[4];
#pragma unroll
    for (int ct = 0; ct < 4; ++ct) {
      int row = ct*16 + l15;
      bk[ct] = *(const bhalf8*)&KSs[(row<<6) + ((((ks<<2)+quad) ^ (row&7))<<3)];
    }
#pragma unroll
    for (int ct = 0; ct < 4; ++ct)
      sacc[ct] = __builtin_amdgcn_mfma_f32_16x16x32_bf16(aq[ks], bk[ct], sacc[ct], 0, 0, 0);
  }
  __syncthreads();                     // all waves done reading KSs -> reuse as Ss
#pragma unroll
  for (int ct = 0; ct < 4; ++ct) {
    float cf = colf0[ct];
    int colg = (ct<<1) + (l15>>3);
    int m = ct*16 + l15;
#pragma unroll
    for (int r = 0; r < 4; ++r) {
      int row = wrow + (quad<<2) + r;
      float v = (row >= m) ? sacc[ct][r] * (rowf[r] * cf) : 0.f;
      KSs[(row<<6) + ((colg ^ ((row>>1)&7))<<3) + (l15&7)] = f2bf(v);
    }
  }
  // no barrier: wave reads back only its own Ss rows
  floatx4 oacc[4] = {};
#pragma unroll
  for (int ks = 0; ks < 2; ++ks) {
    int row = wrow + l15;
    bhalf8 as_ = *(const bhalf8*)&KSs[(row<<6) + ((((ks<<2)+quad) ^ ((row>>1)&7))<<3)];
    bhalf8 bv[4];
#pragma unroll
    for (int ct = 0; ct < 4; ++ct) {
      int vrow = ct*16 + l15;
      bv[ct] = *(const bhalf8*)&Vs[(vrow<<6) + ((((ks<<2)+quad) ^ (vrow&7))<<3)];
    }
#pragma unroll
    for (int ct = 0; ct < 4; ++ct)
      oacc[ct] = __builtin_amdgcn_mfma_f32_16x16x32_bf16(as_, bv[ct], oacc[ct], 0, 0, 0);
  }

  // ---- inter: O += gamma^i/8 * Q @ St ----
  if (has_state) {
    floatx4 iacc[4] = {};
#pragma unroll
    for (int ks = 0; ks < 2; ++ks) {
      bhalf8 bhf[4], blf[4];
#pragma unroll
      for (int ct = 0; ct < 4; ++ct) {
        int er = ct*16 + l15;
        int ga = ((((ks<<2)+quad) ^ (er&7))<<3);
        bhf[ct] = *(const bhalf8*)&Sh[(er<<6) + ga];
        blf[ct] = *(const bhalf8*)&Sl[(er<<6) + ga];
      }
#pragma unroll
      for (int ct = 0; ct < 4; ++ct) {
        iacc[ct] = __builtin_amdgcn_mfma_f32_16x16x32_bf16(aq[ks], bhf[ct], iacc[ct], 0, 0, 0);
        iacc[ct] = __builtin_amdgcn_mfma_f32_16x16x32_bf16(aq[ks], blf[ct], iacc[ct], 0, 0, 0);
      }
    }
#pragma unroll
    for (int ct = 0; ct < 4; ++ct)
#pragma unroll
      for (int r = 0; r < 4; ++r)
        oacc[ct][r] += rowf[r] * iacc[ct][r];
  }

  // ---- fused GroupNorm over DH, write (B,T,C) bf16 ----
#pragma unroll
  for (int r = 0; r < 4; ++r) {
    float s1 = oacc[0][r] + oacc[1][r] + oacc[2][r] + oacc[3][r];
    float s2 = oacc[0][r]*oacc[0][r] + oacc[1][r]*oacc[1][r]
             + oacc[2][r]*oacc[2][r] + oacc[3][r]*oacc[3][r];
#pragma unroll
    for (int off = 1; off < 16; off <<= 1) {
      s1 += __shfl_xor(s1, off);
      s2 += __shfl_xor(s2, off);
    }
    float mean = s1 * (1.f/64.f);
    float var  = s2 * (1.f/64.f) - mean*mean;
    float rstd = rsqrtf(var + 1e-5f);
    int t = n0 + wrow + (quad<<2) + r;
    size_t obase = ((size_t)b*T_ + t)*C_ + h*DH_;
#pragma unroll
    for (int ct = 0; ct < 4; ++ct) {
      int d = ct*16 + l15;
      float y = (oacc[ct][r] - mean)*rstd*gnw[h*DH_ + d] + gnb[h*DH_ + d];
      Xn[obase + d] = f2bf(y);
    }
  }
}

extern "C" void kernel_launch(void* const* d_in, const int* in_sizes, int n_in,
                              void* d_out, int out_size, void* d_ws, size_t ws_size,
                              hipStream_t stream) {
  (void)in_sizes; (void)n_in; (void)out_size; (void)ws_size;
  const float* x   = (const float*)d_in[0];
  const float* Wq  = (const float*)d_in[1];
  const float* Wk  = (const float*)d_in[2];
  const float* Wv  = (const float*)d_in[3];
  const float* Wo  = (const float*)d_in[4];
  const float* gnw = (const float*)d_in[5];
  const float* gnb = (const float*)d_in[6];
  float* out = (float*)d_out;

  char* ws = (char*)d_ws;                 // 48 MB used
  short* Xb   = (short*)(ws);             // [0,8): x bf16; reused as Ktb after qkv
  short* Ktb  = (short*)(ws);             //   K^T (B,H,DH,T)
  short* Wqb  = (short*)(ws + (8u<<20));  // [8,12): Wq+Wk bf16; reused as Pseg (4 MB)
  short* Pseg = (short*)(ws + (8u<<20));  //   segment states, 32*8*2*4096 shorts
  short* Wkb  = (short*)(ws + (10u<<20));
  short* Wvb  = (short*)(ws + (12u<<20));
  short* Wob  = (short*)(ws + (14u<<20));
  short* Qb   = (short*)(ws + (16u<<20)); // (B,H,T,DH)
  short* Kb   = (short*)(ws + (24u<<20)); // (B,H,T,DH)
  short* Vtw  = (short*)(ws + (32u<<20)); // V^T (B,H,DH,T)
  short* Xn   = (short*)(ws + (40u<<20)); // retention out (B,T,C) bf16

  cvt_all<<<(M_*C_/4 + 4*(C_*C_/4)) / 256, 256, 0, stream>>>(
      x, Wq, Wk, Wv, Wo, Xb, Wqb, Wkb, Wvb, Wob);

  gemm_qkv<<<dim3(192), 512, 0, stream>>>(Xb, Wqb, Wkb, Wvb, Qb, Kb, Vtw);
  transpose_k<<<1024, 256, 0, stream>>>(Kb, Ktb);
  seg_state<<<256, 256, 0, stream>>>(Ktb, Vtw, Pseg);
  retention_chunk<<<1024, 256, 0, stream>>>(Qb, Kb, Ktb, Vtw, Pseg, gnw, gnb, Xn);
  gemm_out<<<dim3(16, 32), 256, 0, stream>>>(Xn, Wob, out);
}

// Round 2
// 165.471 us; speedup vs baseline: 1.0599x; 1.0287x over previous
//
#include <hip/hip_runtime.h>
#include <stdint.h>

#define B_ 2
#define T_ 2048
#define C_ 1024
#define H_ 16
#define DH_ 64
#define M_ (B_*T_)   // 4096

typedef short bhalf8 __attribute__((ext_vector_type(8)));
typedef float floatx4 __attribute__((ext_vector_type(4)));

__device__ __forceinline__ short f2bf(float f) {
  unsigned u = __float_as_uint(f);
  u += 0x7fffu + ((u >> 16) & 1u);   // round-to-nearest-even
  return (short)(u >> 16);
}
__device__ __forceinline__ float bf2f(short s) {
  return __uint_as_float(((unsigned)(unsigned short)s) << 16);
}

// async global->LDS, 16B per lane; lds_dst wave-uniform (lane -> +lane*16)
__device__ __forceinline__ void gll16(void* lds_dst, const void* g_src) {
  __builtin_amdgcn_global_load_lds(
      reinterpret_cast<const uint32_t __attribute__((address_space(1)))*>(
          reinterpret_cast<uintptr_t>(g_src)),
      reinterpret_cast<uint32_t __attribute__((address_space(3)))*>(
          reinterpret_cast<uintptr_t>(lds_dst)),
      16, 0, 0);
}

__global__ void cvt_all(
    const float* __restrict__ x,  const float* __restrict__ wq,
    const float* __restrict__ wk, const float* __restrict__ wv,
    const float* __restrict__ wo,
    short* __restrict__ xb, short* __restrict__ wqb, short* __restrict__ wkb,
    short* __restrict__ wvb, short* __restrict__ wob)
{
  int i = blockIdx.x * blockDim.x + threadIdx.x;
  const float* s; short* d; int off;
  if (i < (M_*C_/4)) { s = x; d = xb; off = i; }
  else {
    int j = i - M_*C_/4;
    int w = j >> 18;                     // C_*C_/4 == 1<<18
    off = j & ((1<<18) - 1);
    s = (w==0) ? wq : (w==1) ? wk : (w==2) ? wv : wo;
    d = (w==0) ? wqb : (w==1) ? wkb : (w==2) ? wvb : wob;
  }
  float4 v = ((const float4*)s)[off];
  short4 o;
  o.x = f2bf(v.x); o.y = f2bf(v.y); o.z = f2bf(v.z); o.w = f2bf(v.w);
  ((short4*)d)[off] = o;
}

// R11: fused Q/K/V projection, 256x256 tile, BK=64, 8 waves (2Mx4N),
// 128 KiB LDS, deep pipeline with counted vmcnt (no vmcnt(0) in main loop).
// Grid 192 = 12 N-tiles (x<4 Q, x<8 K, x>=8 V; V swaps operands so C/D
// layout gives coalesced V^T store) x 16 M-tiles, XCD-swizzled.
// NEW in R11: K-blocks also emit K^T (B,H,DH,T) via an LDS-transpose
// epilogue (replaces the separate transpose_k kernel). After the main loop
// the 128 KiB As/Bs LDS is dead; reuse it as a 256x256 bf16 tile Ct.
__global__ __launch_bounds__(512, 2) void gemm_qkv(
    const short* __restrict__ X,
    const short* __restrict__ Wq, const short* __restrict__ Wk, const short* __restrict__ Wv,
    short* __restrict__ Qb, short* __restrict__ Kb, short* __restrict__ Vt,
    short* __restrict__ Kt)
{
  __shared__ __align__(16) short SM[4*256*64];            // 128 KiB
  short (*As)[256*64] = (short (*)[256*64])(SM);
  short (*Bs)[256*64] = (short (*)[256*64])(SM + 2*256*64);
  short* Ct = SM;                                          // 256x256 epilogue tile

  const int tid  = threadIdx.x;
  const int lane = tid & 63;
  const int wid  = tid >> 6;
  const int l15  = lane & 15;
  const int quad = lane >> 4;
  const int wr   = wid >> 2;          // 0..1  (M half)
  const int wc   = wid & 3;           // 0..3  (N quarter)
  const int K    = C_;

  // XCD-aware swizzle: 192 % 8 == 0, consecutive wg share m-tile in runs of 12
  const int bid = blockIdx.x;
  const int wg  = (bid & 7) * 24 + (bid >> 3);
  const int nx  = wg % 12;
  const int m0  = (wg / 12) << 8;

  int kind, nloc;                    // 0=Q 1=K 2=V
  const short *Ab, *Bb;
  if (nx < 4)      { kind = 0; nloc = nx << 8;       Ab = X  + (size_t)m0*K;   Bb = Wq + (size_t)nloc*K; }
  else if (nx < 8) { kind = 1; nloc = (nx - 4) << 8; Ab = X  + (size_t)m0*K;   Bb = Wk + (size_t)nloc*K; }
  else             { kind = 2; nloc = (nx - 8) << 8; Ab = Wv + (size_t)nloc*K; Bb = X  + (size_t)m0*K;   }

  const int r_loc = tid >> 3;        // 0..63: row within a 64-row quarter
  const int g_lin = tid & 7;         // linear granule (16B) within row

  // stage one 8 KB quarter-unit (64 rows x 64 shorts): 1 gll16/thread
  auto stageU = [&](short* lds, const short* g, int q, int k0) {
    int row = (q << 6) + r_loc;
    int gs  = g_lin ^ (row & 7);     // pre-swizzled global source (m173)
    gll16(lds + (q << 12) + (wid << 9), g + (size_t)row * K + k0 + (gs << 3));
  };

  floatx4 acc[8][4] = {};

  // ---- prologue: stage tile 0; order = read priority of tile0.p1/p2 ----
  stageU(&Bs[0][0], Bb, 0, 0); stageU(&Bs[0][0], Bb, 1, 0);
  stageU(&Bs[0][0], Bb, 2, 0); stageU(&Bs[0][0], Bb, 3, 0);
  stageU(&As[0][0], Ab, 0, 0); stageU(&As[0][0], Ab, 2, 0);
  stageU(&As[0][0], Ab, 1, 0); stageU(&As[0][0], Ab, 3, 0);
  asm volatile("s_waitcnt vmcnt(2)" ::: "memory");   // allow A q1,q3 in flight
  __builtin_amdgcn_s_barrier();
  __builtin_amdgcn_sched_barrier(0);

  for (int t = 0; t < 16; ++t) {
    const int buf = t & 1, nbuf = buf ^ 1;
    const int kn = (t + 1) << 6;
    const bool pf = (t < 15);
    bhalf8 aF[4], bF[4];

    // -------- phase 1: ks=0, m-frags 0..3 (+ B ks=0) --------
#pragma unroll
    for (int i = 0; i < 4; ++i) {
      int row = (wr << 7) + (i << 4) + l15;
      aF[i] = *(const bhalf8*)&As[buf][(row << 6) + ((quad ^ (row & 7)) << 3)];
    }
#pragma unroll
    for (int n = 0; n < 4; ++n) {
      int row = (wc << 6) + (n << 4) + l15;
      bF[n] = *(const bhalf8*)&Bs[buf][(row << 6) + ((quad ^ (row & 7)) << 3)];
    }
    if (pf) { stageU(&Bs[nbuf][0], Bb, 0, kn); stageU(&Bs[nbuf][0], Bb, 1, kn); }
    __builtin_amdgcn_s_barrier();
    asm volatile("s_waitcnt lgkmcnt(0)" ::: "memory");
    __builtin_amdgcn_sched_barrier(0);
    __builtin_amdgcn_s_setprio(1);
#pragma unroll
    for (int i = 0; i < 4; ++i)
#pragma unroll
      for (int n = 0; n < 4; ++n)
        acc[i][n] = __builtin_amdgcn_mfma_f32_16x16x32_bf16(aF[i], bF[n], acc[i][n], 0, 0, 0);
    __builtin_amdgcn_s_setprio(0);
    asm volatile("s_waitcnt vmcnt(2)" ::: "memory");
    __builtin_amdgcn_s_barrier();
    __builtin_amdgcn_sched_barrier(0);

    // -------- phase 2: ks=0, m-frags 4..7 (reuse bF) --------
#pragma unroll
    for (int i = 0; i < 4; ++i) {
      int row = (wr << 7) + ((4 + i) << 4) + l15;
      aF[i] = *(const bhalf8*)&As[buf][(row << 6) + ((quad ^ (row & 7)) << 3)];
    }
    if (pf) { stageU(&Bs[nbuf][0], Bb, 2, kn); stageU(&Bs[nbuf][0], Bb, 3, kn); }
    __builtin_amdgcn_s_barrier();
    asm volatile("s_waitcnt lgkmcnt(0)" ::: "memory");
    __builtin_amdgcn_sched_barrier(0);
    __builtin_amdgcn_s_setprio(1);
#pragma unroll
    for (int i = 0; i < 4; ++i)
#pragma unroll
      for (int n = 0; n < 4; ++n)
        acc[4 + i][n] = __builtin_amdgcn_mfma_f32_16x16x32_bf16(aF[i], bF[n], acc[4 + i][n], 0, 0, 0);
    __builtin_amdgcn_s_setprio(0);
    asm volatile("s_waitcnt vmcnt(4)" ::: "memory");
    __builtin_amdgcn_s_barrier();
    __builtin_amdgcn_sched_barrier(0);

    // -------- phase 3: ks=1, m-frags 0..3 (+ B ks=1) --------
#pragma unroll
    for (int i = 0; i < 4; ++i) {
      int row = (wr << 7) + (i << 4) + l15;
      aF[i] = *(const bhalf8*)&As[buf][(row << 6) + (((4 + quad) ^ (row & 7)) << 3)];
    }
#pragma unroll
    for (int n = 0; n < 4; ++n) {
      int row = (wc << 6) + (n << 4) + l15;
      bF[n] = *(const bhalf8*)&Bs[buf][(row << 6) + (((4 + quad) ^ (row & 7)) << 3)];
    }
    if (pf) { stageU(&As[nbuf][0], Ab, 0, kn); stageU(&As[nbuf][0], Ab, 2, kn); }
    __builtin_amdgcn_s_barrier();
    asm volatile("s_waitcnt lgkmcnt(0)" ::: "memory");
    __builtin_amdgcn_sched_barrier(0);
    __builtin_amdgcn_s_setprio(1);
#pragma unroll
    for (int i = 0; i < 4; ++i)
#pragma unroll
      for (int n = 0; n < 4; ++n)
        acc[i][n] = __builtin_amdgcn_mfma_f32_16x16x32_bf16(aF[i], bF[n], acc[i][n], 0, 0, 0);
    __builtin_amdgcn_s_setprio(0);
    asm volatile("s_waitcnt vmcnt(6)" ::: "memory");
    __builtin_amdgcn_s_barrier();
    __builtin_amdgcn_sched_barrier(0);

    // -------- phase 4: ks=1, m-frags 4..7 (reuse bF) --------
#pragma unroll
    for (int i = 0; i < 4; ++i) {
      int row = (wr << 7) + ((4 + i) << 4) + l15;
      aF[i] = *(const bhalf8*)&As[buf][(row << 6) + (((4 + quad) ^ (row & 7)) << 3)];
    }
    if (pf) { stageU(&As[nbuf][0], Ab, 1, kn); stageU(&As[nbuf][0], Ab, 3, kn); }
    __builtin_amdgcn_s_barrier();
    asm volatile("s_waitcnt lgkmcnt(0)" ::: "memory");
    __builtin_amdgcn_sched_barrier(0);
    __builtin_amdgcn_s_setprio(1);
#pragma unroll
    for (int i = 0; i < 4; ++i)
#pragma unroll
      for (int n = 0; n < 4; ++n)
        acc[4 + i][n] = __builtin_amdgcn_mfma_f32_16x16x32_bf16(aF[i], bF[n], acc[4 + i][n], 0, 0, 0);
    __builtin_amdgcn_s_setprio(0);
    asm volatile("s_waitcnt vmcnt(2)" ::: "memory");
    __builtin_amdgcn_s_barrier();
    __builtin_amdgcn_sched_barrier(0);
  }
  // after the final phase-4 barrier every wave is done with As/Bs -> Ct reusable

  if (kind < 2) {                        // Q or K: RoPE epilogue -> (B,H,T,DH)
    short* Cb = kind ? Kb : Qb;
    const int hh = (nloc + (wc << 6)) >> 6;     // wave's 64-col chunk = 1 head
    const float frq0 = exp2f((float)l15        * (-0.4152410118609203f));
    const float frq1 = exp2f((float)(l15 + 16) * (-0.4152410118609203f));
    const int swz = (l15 & 7) << 3;             // Ct granule swizzle key (c&7 == l15&7)
#pragma unroll
    for (int m = 0; m < 8; ++m)
#pragma unroll
      for (int r = 0; r < 4; ++r) {
        int tl = (wr << 7) + (m << 4) + (quad << 2) + r;   // token within 256-tile
        int n  = m0 + tl;
        int bb = n >> 11, tt = n & (T_ - 1);
        size_t base = ((size_t)(bb * H_ + hh) * T_ + tt) * DH_;
        float tf = (float)tt;
        float v0, v1, v2, v3;
        {
          float ang = tf * frq0;
          float sn = __sinf(ang), cs = __cosf(ang);
          float xlo = acc[m][0][r], xhi = acc[m][2][r];
          v0 = xlo * cs - xhi * sn;
          v1 = xhi * cs + xlo * sn;
          Cb[base + l15]      = f2bf(v0);
          Cb[base + l15 + 32] = f2bf(v1);
        }
        {
          float ang = tf * frq1;
          float sn = __sinf(ang), cs = __cosf(ang);
          float xlo = acc[m][1][r], xhi = acc[m][3][r];
          v2 = xlo * cs - xhi * sn;
          v3 = xhi * cs + xlo * sn;
          Cb[base + l15 + 16] = f2bf(v2);
          Cb[base + l15 + 48] = f2bf(v3);
        }
        if (kind == 1) {                 // also deposit into Ct for K^T emit
          int tswz = tl ^ swz;           // XOR t-granule bits with c&7
          int cb = (wc << 6);
          Ct[(cb + l15)      * 256 + tswz] = f2bf(v0);
          Ct[(cb + l15 + 32) * 256 + tswz] = f2bf(v1);
          Ct[(cb + l15 + 16) * 256 + tswz] = f2bf(v2);
          Ct[(cb + l15 + 48) * 256 + tswz] = f2bf(v3);
        }
      }
    if (kind == 1) {                     // coalesced K^T store from Ct
      __syncthreads();
      const int hb = nloc >> 6;
#pragma unroll
      for (int rr = 0; rr < 16; ++rr) {
        int lin = rr * 512 + tid;        // 8192 16B-chunks = 256 c x 32 granules
        int cc_ = lin >> 5;              // column (head-local channel)
        int g   = lin & 31;              // t-granule (8 tokens)
        bhalf8 v = *(const bhalf8*)&Ct[cc_ * 256 + ((g ^ (cc_ & 7)) << 3)];
        int tg = m0 + (g << 3);
        int bb = tg >> 11, tt = tg & (T_ - 1);
        size_t dst = ((size_t)(bb * H_ + hb + (cc_ >> 6)) * DH_ + (cc_ & 63)) * T_ + tt;
        *(bhalf8*)&Kt[dst] = v;
      }
    }
  } else {                               // V: rows=channels, cols=tokens -> V^T
#pragma unroll
    for (int m = 0; m < 8; ++m)
#pragma unroll
      for (int r = 0; r < 4; ++r) {
        int o = nloc + (wr << 7) + (m << 4) + (quad << 2) + r;
#pragma unroll
        for (int n = 0; n < 4; ++n) {
          int tk = m0 + (wc << 6) + (n << 4) + l15;
          int bb = tk >> 11, tt = tk & (T_ - 1);
          Vt[(size_t)bb * (C_ * T_) + (size_t)o * T_ + tt] = f2bf(acc[m][n][r]);
        }
      }
  }
}

// Final projection. R11: BK=64 (was 32) -> 64 MFMA per barrier-drain per
// block (m97 ratio), LDS 48 KB (3 blocks/CU by LDS, grid 512 -> 2/CU).
__global__ __launch_bounds__(256) void gemm_out(
    const short* __restrict__ A, const short* __restrict__ Bm, float* __restrict__ Cf)
{
  __shared__ __align__(16) short As[2][128*64];   // 16 KB per buf
  __shared__ __align__(16) short Bs[2][64*64];    // 8 KB per buf
  const int tid = threadIdx.x, lane = tid & 63, wv = tid >> 6;
  const int l15 = lane & 15, quad = lane >> 4;
  const int n0 = blockIdx.x << 6;
  const int m0 = blockIdx.y << 7;

  const short* Ab = A  + (size_t)m0 * C_;
  const short* Bb = Bm + (size_t)n0 * C_;

  auto stage = [&](int buf, int k0) {
#pragma unroll
    for (int i = 0; i < 4; ++i) {                  // A: 128 rows x 8 granules
      int slot = (i<<8) + tid, r = slot >> 3, g = (slot & 7) ^ (r & 7);
      gll16(&As[buf][((i<<8) + (wv<<6))*8], Ab + (size_t)r*C_ + k0 + (g<<3));
    }
#pragma unroll
    for (int i = 0; i < 2; ++i) {                  // B: 64 rows x 8 granules
      int slot = (i<<8) + tid, r = slot >> 3, g = (slot & 7) ^ (r & 7);
      gll16(&Bs[buf][((i<<8) + (wv<<6))*8], Bb + (size_t)r*C_ + k0 + (g<<3));
    }
  };

  floatx4 acc[2][4] = {};
  stage(0, 0);
  int cur = 0;
  for (int it = 0; it < 16; ++it) {
    __syncthreads();
    if (it < 15) stage(cur ^ 1, (it + 1) << 6);
    bhalf8 af[2][2], bfr[2][4];
#pragma unroll
    for (int ks = 0; ks < 2; ++ks) {
#pragma unroll
      for (int rt = 0; rt < 2; ++rt) {
        int row = (wv<<5) + rt*16 + l15;
        af[ks][rt] = *(const bhalf8*)&As[cur][(row<<6) + ((((ks<<2)+quad) ^ (row&7))<<3)];
      }
#pragma unroll
      for (int ct = 0; ct < 4; ++ct) {
        int row = ct*16 + l15;
        bfr[ks][ct] = *(const bhalf8*)&Bs[cur][(row<<6) + ((((ks<<2)+quad) ^ (row&7))<<3)];
      }
    }
#pragma unroll
    for (int ks = 0; ks < 2; ++ks)
#pragma unroll
      for (int rt = 0; rt < 2; ++rt)
#pragma unroll
        for (int ct = 0; ct < 4; ++ct)
          acc[rt][ct] = __builtin_amdgcn_mfma_f32_16x16x32_bf16(af[ks][rt], bfr[ks][ct], acc[rt][ct], 0, 0, 0);
    cur ^= 1;
  }

#pragma unroll
  for (int rt = 0; rt < 2; ++rt)
#pragma unroll
    for (int r = 0; r < 4; ++r) {
      int n = m0 + (wv<<5) + rt*16 + quad*4 + r;
#pragma unroll
      for (int ct = 0; ct < 4; ++ct)
        Cf[(size_t)n * C_ + n0 + ct*16 + l15] = acc[rt][ct][r];
    }
}

// Per-segment state summaries. 256 blocks = bh*8 + p, single-barrier dbuf.
__global__ __launch_bounds__(256) void seg_state(
    const short* __restrict__ Kt, const short* __restrict__ Vt,
    short* __restrict__ Pseg)
{
  __shared__ __align__(16) short Ks[2][64*64];   // K^T [d][tok], swizzled
  __shared__ __align__(16) short Vs[2][64*64];   // V^T [e][tok], swizzled
  const int tid = threadIdx.x, lane = tid & 63, wv = tid >> 6;
  const int l15 = lane & 15, quad = lane >> 4;
  const int wrow = wv << 4;
  const int bh = blockIdx.x >> 3, p = blockIdx.x & 7;
  const int h = bh & 15;
  const float log2g = log2f(1.f - exp2f(-5.f - (float)h));
  const float g64 = exp2f(log2g * 64.f);

  float wgt[16];
#pragma unroll
  for (int ks = 0; ks < 2; ++ks)
#pragma unroll
    for (int i = 0; i < 8; ++i)
      wgt[ks*8 + i] = exp2f(log2g * (float)(64 - (ks*32 + (quad<<3) + i)));

  const short* Ktg = Kt + (size_t)bh*DH_*T_;
  const short* Vtg = Vt + (size_t)bh*DH_*T_;

  auto stage = [&](int buf, int jc) {
    const int m0 = ((p<<2) + jc) << 6;
#pragma unroll
    for (int i = 0; i < 2; ++i) {
      int slot = (i<<8) + tid;
      int r = slot >> 3, g = (slot & 7) ^ (r & 7);
      gll16(&Ks[buf][((i<<8) + (wv<<6))*8], Ktg + (size_t)r*T_ + m0 + (g<<3));
      gll16(&Vs[buf][((i<<8) + (wv<<6))*8], Vtg + (size_t)r*T_ + m0 + (g<<3));
    }
  };

  floatx4 acc[4] = {};
  stage(0, 0);
  int cur = 0;
  for (int j = 0; j < 4; ++j) {
    __syncthreads();
    if (j < 3) stage(cur ^ 1, j + 1);
#pragma unroll
    for (int ct = 0; ct < 4; ++ct)
#pragma unroll
      for (int r = 0; r < 4; ++r) acc[ct][r] *= g64;
#pragma unroll
    for (int ks = 0; ks < 2; ++ks) {
      int row = wrow + l15;
      bhalf8 va = *(const bhalf8*)&Vs[cur][(row<<6) + ((((ks<<2)+quad) ^ (row&7))<<3)];
      bhalf8 aw;
#pragma unroll
      for (int i = 0; i < 8; ++i) aw[i] = f2bf(bf2f(va[i]) * wgt[ks*8 + i]);
      bhalf8 bk[4];
#pragma unroll
      for (int ct = 0; ct < 4; ++ct) {
        int kr = ct*16 + l15;
        bk[ct] = *(const bhalf8*)&Ks[cur][(kr<<6) + ((((ks<<2)+quad) ^ (kr&7))<<3)];
      }
#pragma unroll
      for (int ct = 0; ct < 4; ++ct)
        acc[ct] = __builtin_amdgcn_mfma_f32_16x16x32_bf16(aw, bk[ct], acc[ct], 0, 0, 0);
    }
    cur ^= 1;
  }
  size_t base = (size_t)(bh*8 + p) * 2 * 4096;
#pragma unroll
  for (int ct = 0; ct < 4; ++ct)
#pragma unroll
    for (int r = 0; r < 4; ++r) {
      int e = wrow + (quad<<2) + r, d = ct*16 + l15;
      float x = acc[ct][r];
      short hi = f2bf(x);
      short lo = f2bf(x - bf2f(hi));
      Pseg[base + e*64 + d]        = hi;
      Pseg[base + 4096 + e*64 + d] = lo;
    }
}

// Chunked retention: grid 1024 uniform blocks = (bh, chunk).
__global__ __launch_bounds__(256) void retention_chunk(
    const short* __restrict__ Qb, const short* __restrict__ Kb,
    const short* __restrict__ Kt, const short* __restrict__ Vt,
    const short* __restrict__ Pseg,
    const float* __restrict__ gnw, const float* __restrict__ gnb,
    short* __restrict__ Xn)
{
  __shared__ __align__(16) short Vs[64*64];    // V^T [e][tok] (scan, then own)
  __shared__ __align__(16) short Kts[64*64];   // K^T [d][tok] (scan)
  __shared__ __align__(16) short KSs[64*64];   // K [tok][d], reused as Ss
  __shared__ __align__(16) short Sh[64*64];    // state hi [e][d]
  __shared__ __align__(16) short Sl[64*64];    // state lo [e][d]

  const int tid = threadIdx.x, lane = tid & 63, wv = tid >> 6;
  const int l15 = lane & 15, quad = lane >> 4;
  const int wrow = wv << 4;

  const int idx = blockIdx.x;
  const int bh = idx & 31;
  const int cc = idx >> 5;
  const int c  = ((cc & 7) << 2) | (cc >> 3);
  const int p = c >> 2, j = c & 3;
  const int b = bh >> 4, h = bh & 15;
  const int n0 = c << 6;

  const float log2g = log2f(1.f - exp2f(-5.f - (float)h));
  const float g64 = exp2f(log2g * 64.f);

  const short* Qg  = Qb + ((size_t)bh*T_ + n0 + wrow) * DH_;
  const short* Kg  = Kb + (size_t)bh*T_*DH_;
  const short* Ktg = Kt + (size_t)bh*DH_*T_;
  const short* Vtg = Vt + (size_t)bh*DH_*T_;

  bhalf8 aq[2];
#pragma unroll
  for (int ks = 0; ks < 2; ++ks)
    aq[ks] = *(const bhalf8*)(Qg + (size_t)l15*DH_ + ks*32 + quad*8);

  float rowf[4], colf0[4];
#pragma unroll
  for (int r = 0; r < 4; ++r)
    rowf[r] = exp2f(log2g * (float)(wrow + (quad<<2) + r)) * 0.125f;
#pragma unroll
  for (int ct = 0; ct < 4; ++ct)
    colf0[ct] = exp2f(-log2g * (float)(ct*16 + l15));

  const bool has_state = (c > 0);

  // ---- state scan over own-segment chunks 0..j-1 ----
  floatx4 st[4] = {};
  if (j > 0) {
    float wgt[16];
#pragma unroll
    for (int ks = 0; ks < 2; ++ks)
#pragma unroll
      for (int i = 0; i < 8; ++i)
        wgt[ks*8 + i] = exp2f(log2g * (float)(64 - (ks*32 + (quad<<3) + i)));
    for (int jp = 0; jp < j; ++jp) {
      if (log2g * (float)((j - 1 - jp) << 6) < -34.f) continue; // fully decayed
      const int m0 = ((p<<2) + jp) << 6;
      __syncthreads();
#pragma unroll
      for (int i = 0; i < 2; ++i) {
        int slot = (i<<8) + tid;
        int r = slot >> 3, g = (slot & 7) ^ (r & 7);
        gll16(&Kts[((i<<8) + (wv<<6))*8], Ktg + (size_t)r*T_ + m0 + (g<<3));
        gll16(&Vs[((i<<8) + (wv<<6))*8],  Vtg + (size_t)r*T_ + m0 + (g<<3));
      }
      __syncthreads();
#pragma unroll
      for (int ct = 0; ct < 4; ++ct)
#pragma unroll
        for (int r = 0; r < 4; ++r) st[ct][r] *= g64;
#pragma unroll
      for (int ks = 0; ks < 2; ++ks) {
        int row = wrow + l15;
        bhalf8 va = *(const bhalf8*)&Vs[(row<<6) + ((((ks<<2)+quad) ^ (row&7))<<3)];
        bhalf8 aw;
#pragma unroll
        for (int i = 0; i < 8; ++i) aw[i] = f2bf(bf2f(va[i]) * wgt[ks*8 + i]);
        bhalf8 bk[4];
#pragma unroll
        for (int ct = 0; ct < 4; ++ct) {
          int kr = ct*16 + l15;
          bk[ct] = *(const bhalf8*)&Kts[(kr<<6) + ((((ks<<2)+quad) ^ (kr&7))<<3)];
        }
#pragma unroll
        for (int ct = 0; ct < 4; ++ct)
          st[ct] = __builtin_amdgcn_mfma_f32_16x16x32_bf16(aw, bk[ct], st[ct], 0, 0, 0);
      }
    }
  }
  // ---- add weighted previous-segment summaries (256-token segments) ----
  for (int pp = 0; pp < p; ++pp) {
    float wexp = log2g * (float)(n0 - ((pp + 1) << 8));
    if (wexp < -34.f) continue;
    float w = exp2f(wexp);
    const short* Pg = Pseg + (size_t)(bh*8 + pp) * 2 * 4096;
#pragma unroll
    for (int ct = 0; ct < 4; ++ct)
#pragma unroll
      for (int r = 0; r < 4; ++r) {
        int e = wrow + (quad<<2) + r, d = ct*16 + l15;
        st[ct][r] += w * (bf2f(Pg[e*64 + d]) + bf2f(Pg[4096 + e*64 + d]));
      }
  }
  // ---- split state to bf16 hi/lo in LDS ----
  if (has_state) {
#pragma unroll
    for (int ct = 0; ct < 4; ++ct)
#pragma unroll
      for (int r = 0; r < 4; ++r) {
        int e = wrow + (quad<<2) + r, d = ct*16 + l15;
        float x = st[ct][r];
        short hi = f2bf(x);
        short lo = f2bf(x - bf2f(hi));
        int addr = (e<<6) + ((((d>>3) ^ (e&7))<<3)) + (d&7);
        Sh[addr] = hi; Sl[addr] = lo;
      }
  }

  // ---- stage own chunk: K token-major + V^T ----
  __syncthreads();                     // covers Sh/Sl writes + frees Vs/Kts
#pragma unroll
  for (int i = 0; i < 2; ++i) {
    int slot = (i<<8) + tid;
    int r = slot >> 3, g = (slot & 7) ^ (r & 7);
    gll16(&KSs[((i<<8) + (wv<<6))*8], Kg  + (size_t)(n0 + r)*DH_ + (g<<3));
    gll16(&Vs[((i<<8) + (wv<<6))*8],  Vtg + (size_t)r*T_ + n0 + (g<<3));
  }
  __syncthreads();

  // ---- intra: QK^T on diagonal chunk ----
  floatx4 sacc[4] = {};
#pragma unroll
  for (int ks = 0; ks < 2; ++ks) {
    bhalf8 bk[4];
#pragma unroll
    for (int ct = 0; ct < 4; ++ct) {
      int row = ct*16 + l15;
      bk[ct] = *(const bhalf8*)&KSs[(row<<6) + ((((ks<<2)+quad) ^ (row&7))<<3)];
    }
#pragma unroll
    for (int ct = 0; ct < 4; ++ct)
      sacc[ct] = __builtin_amdgcn_mfma_f32_16x16x32_bf16(aq[ks], bk[ct], sacc[ct], 0, 0, 0);
  }
  __syncthreads();                     // all waves done reading KSs -> reuse as Ss
#pragma unroll
  for (int ct = 0; ct < 4; ++ct) {
    float cf = colf0[ct];
    int colg = (ct<<1) + (l15>>3);
    int m = ct*16 + l15;
#pragma unroll
    for (int r = 0; r < 4; ++r) {
      int row = wrow + (quad<<2) + r;
      float v = (row >= m) ? sacc[ct][r] * (rowf[r] * cf) : 0.f;
      KSs[(row<<6) + ((colg ^ ((row>>1)&7))<<3) + (l15&7)] = f2bf(v);
    }
  }
  // no barrier: wave reads back only its own Ss rows
  floatx4 oacc[4] = {};
#pragma unroll
  for (int ks = 0; ks < 2; ++ks) {
    int row = wrow + l15;
    bhalf8 as_ = *(const bhalf8*)&KSs[(row<<6) + ((((ks<<2)+quad) ^ ((row>>1)&7))<<3)];
    bhalf8 bv[4];
#pragma unroll
    for (int ct = 0; ct < 4; ++ct) {
      int vrow = ct*16 + l15;
      bv[ct] = *(const bhalf8*)&Vs[(vrow<<6) + ((((ks<<2)+quad) ^ (vrow&7))<<3)];
    }
#pragma unroll
    for (int ct = 0; ct < 4; ++ct)
      oacc[ct] = __builtin_amdgcn_mfma_f32_16x16x32_bf16(as_, bv[ct], oacc[ct], 0, 0, 0);
  }

  // ---- inter: O += gamma^i/8 * Q @ St ----
  if (has_state) {
    floatx4 iacc[4] = {};
#pragma unroll
    for (int ks = 0; ks < 2; ++ks) {
      bhalf8 bhf[4], blf[4];
#pragma unroll
      for (int ct = 0; ct < 4; ++ct) {
        int er = ct*16 + l15;
        int ga = ((((ks<<2)+quad) ^ (er&7))<<3);
        bhf[ct] = *(const bhalf8*)&Sh[(er<<6) + ga];
        blf[ct] = *(const bhalf8*)&Sl[(er<<6) + ga];
      }
#pragma unroll
      for (int ct = 0; ct < 4; ++ct) {
        iacc[ct] = __builtin_amdgcn_mfma_f32_16x16x32_bf16(aq[ks], bhf[ct], iacc[ct], 0, 0, 0);
        iacc[ct] = __builtin_amdgcn_mfma_f32_16x16x32_bf16(aq[ks], blf[ct], iacc[ct], 0, 0, 0);
      }
    }
#pragma unroll
    for (int ct = 0; ct < 4; ++ct)
#pragma unroll
      for (int r = 0; r < 4; ++r)
        oacc[ct][r] += rowf[r] * iacc[ct][r];
  }

  // ---- fused GroupNorm over DH, write (B,T,C) bf16 ----
#pragma unroll
  for (int r = 0; r < 4; ++r) {
    float s1 = oacc[0][r] + oacc[1][r] + oacc[2][r] + oacc[3][r];
    float s2 = oacc[0][r]*oacc[0][r] + oacc[1][r]*oacc[1][r]
             + oacc[2][r]*oacc[2][r] + oacc[3][r]*oacc[3][r];
#pragma unroll
    for (int off = 1; off < 16; off <<= 1) {
      s1 += __shfl_xor(s1, off);
      s2 += __shfl_xor(s2, off);
    }
    float mean = s1 * (1.f/64.f);
    float var  = s2 * (1.f/64.f) - mean*mean;
    float rstd = rsqrtf(var + 1e-5f);
    int t = n0 + wrow + (quad<<2) + r;
    size_t obase = ((size_t)b*T_ + t)*C_ + h*DH_;
#pragma unroll
    for (int ct = 0; ct < 4; ++ct) {
      int d = ct*16 + l15;
      float y = (oacc[ct][r] - mean)*rstd*gnw[h*DH_ + d] + gnb[h*DH_ + d];
      Xn[obase + d] = f2bf(y);
    }
  }
}

extern "C" void kernel_launch(void* const* d_in, const int* in_sizes, int n_in,
                              void* d_out, int out_size, void* d_ws, size_t ws_size,
                              hipStream_t stream) {
  (void)in_sizes; (void)n_in; (void)out_size; (void)ws_size;
  const float* x   = (const float*)d_in[0];
  const float* Wq  = (const float*)d_in[1];
  const float* Wk  = (const float*)d_in[2];
  const float* Wv  = (const float*)d_in[3];
  const float* Wo  = (const float*)d_in[4];
  const float* gnw = (const float*)d_in[5];
  const float* gnb = (const float*)d_in[6];
  float* out = (float*)d_out;

  char* ws = (char*)d_ws;                 // 56 MB used (ws >= 256 MB per poison)
  short* Xb   = (short*)(ws);             // [0,8): x bf16
  short* Wqb  = (short*)(ws + (8u<<20));  // [8,12): Wq+Wk bf16; reused as Pseg (4 MB)
  short* Pseg = (short*)(ws + (8u<<20));  //   segment states, 32*8*2*4096 shorts
  short* Wkb  = (short*)(ws + (10u<<20));
  short* Wvb  = (short*)(ws + (12u<<20));
  short* Wob  = (short*)(ws + (14u<<20));
  short* Qb   = (short*)(ws + (16u<<20)); // (B,H,T,DH)
  short* Kb   = (short*)(ws + (24u<<20)); // (B,H,T,DH)
  short* Vtw  = (short*)(ws + (32u<<20)); // V^T (B,H,DH,T)
  short* Xn   = (short*)(ws + (40u<<20)); // retention out (B,T,C) bf16
  short* Ktb  = (short*)(ws + (48u<<20)); // K^T (B,H,DH,T) - written by gemm_qkv

  cvt_all<<<(M_*C_/4 + 4*(C_*C_/4)) / 256, 256, 0, stream>>>(
      x, Wq, Wk, Wv, Wo, Xb, Wqb, Wkb, Wvb, Wob);

  gemm_qkv<<<dim3(192), 512, 0, stream>>>(Xb, Wqb, Wkb, Wvb, Qb, Kb, Vtw, Ktb);
  seg_state<<<256, 256, 0, stream>>>(Ktb, Vtw, Pseg);
  retention_chunk<<<1024, 256, 0, stream>>>(Qb, Kb, Ktb, Vtw, Pseg, gnw, gnb, Xn);
  gemm_out<<<dim3(16, 32), 256, 0, stream>>>(Xn, Wob, out);
}